// Round 9
// baseline (9566.224 us; speedup 1.0000x reference)
//
#include <hip/hip_runtime.h>
#include <math.h>

typedef unsigned long long u64;
typedef unsigned int u32;

#define N_HID   1024
#define NBATCH  128
#define TSTEPS  500
#define DT      0.05f
#define THETA   0.1f

// Geometry identical to bit-exact R5/R8: WG = 256 thr, 8-batch x 64-col tile,
// thread tile 4b x 4c, k-split 8 (KSEG=128). 16 groups x 16 ctiles = 256 WGs,
// 1/CU cooperative. Per-output FP summation order unchanged.
#define B_WG   8
#define C_WG   64
#define KSPL   8
#define KSEG   (N_HID / KSPL)      // 128
#define NGRP   (NBATCH / B_WG)     // 16
#define NCT    (N_HID / C_WG)      // 16
#define NWG    (NGRP * NCT)        // 256

// hy exchange: u64-packed (epoch<<32)|f32 value, ping-pong buffers
// hyU[1024][128]. No flags, no barriers across WGs: consumers spin on the
// per-element epoch. All global sync traffic = R5-proven AGENT-scope relaxed
// atomics (IF$-coherent).
#define CTRL_TOT    0
#define CTRL_WORDS  64

__device__ __forceinline__ u64 a_ld64(const u64* p) {
    return __hip_atomic_load(p, __ATOMIC_RELAXED, __HIP_MEMORY_SCOPE_AGENT);
}
__device__ __forceinline__ void a_st64(u64* p, u64 v) {
    __hip_atomic_store(p, v, __ATOMIC_RELAXED, __HIP_MEMORY_SCOPE_AGENT);
}

__global__ __launch_bounds__(256, 1) void persist_kernel(
    const float* __restrict__ x,
    const float* __restrict__ W,       // (1024,1024) row-major [k][c]
    const float* __restrict__ x2h,
    const float* __restrict__ bias,
    const float* __restrict__ gam,
    const float* __restrict__ eps,
    u64* __restrict__ hyA,             // (1024,128) packed, parity-0 target? (see below)
    u64* __restrict__ hyB,
    float* __restrict__ uout,          // (128,1024)
    u32* __restrict__ ctrl,
    float alpha, float oma)
{
    // parity-double-buffered LDS: one __syncthreads per step total
    __shared__ float sh_hyT[2][N_HID * B_WG / 1];     // 2 x 32 KB
    __shared__ float sh_part[2][KSPL * B_WG * C_WG];  // 2 x 16 KB
    __shared__ u32 sh_cnt;

    const int tid = threadIdx.x;
    if (tid == 0) sh_cnt = 0u;

    // XCD swizzle (R5): XCD (bid&7) owns 2 ctiles -> 512 KB W slice hot in L2.
    const int bid   = blockIdx.x;
    const int xcd   = bid & 7;
    const int idx   = bid >> 3;
    const int ctile = xcd * 2 + (idx & 1);
    const int btile = idx >> 1;
    const int c0g   = ctile * C_WG;
    const int b0    = btile * B_WG;

    // GEMM thread mapping (R5/R8)
    const int cg  = tid & 15;
    const int bg  = (tid >> 4) & 1;
    const int ks  = tid >> 5;          // 0..7
    const int bl0 = bg * 4;
    const int k0  = ks * KSEG;
    const float* Wp = W + (size_t)k0 * N_HID + c0g + cg * 4;

    // wave staging mapping: wave wv owns hy rows [256*wv, 256*wv+256)
    const int wv   = tid >> 6;         // 0..3
    const int lane = tid & 63;

    // epilogue mapping: two outputs per thread
    const int bl_a = tid >> 6;
    const int bl_b = 4 + bl_a;
    const int c_e  = tid & 63;
    const int cgl  = c0g + c_e;
    const float x2h_c  = x2h[cgl];
    const float bias_c = bias[cgl];
    const float gam_c  = gam[cgl];
    const float eps_c  = eps[cgl];
    const float* xrow_a = x + (size_t)(b0 + bl_a) * TSTEPS;
    const float* xrow_b = x + (size_t)(b0 + bl_b) * TSTEPS;

    float hz_a = 0.f, hz_b = 0.f, u_a = 0.f, u_b = 0.f;
    u32 spikes = 0;

    for (int t = 0; t < TSTEPS; ++t) {
        const u64* srcU = (t & 1) ? hyB : hyA;   // holds epoch t (t>=1)
        u64*       dstU = (t & 1) ? hyA : hyB;   // gets epoch t+1
        float* hyt  = sh_hyT[t & 1];
        float* part = sh_part[t & 1];

        const float xa = xrow_a[t];
        const float xb = xrow_b[t];

        float acc[4][4];
        #pragma unroll
        for (int i = 0; i < 4; ++i)
            #pragma unroll
            for (int jj = 0; jj < 4; ++jj) acc[i][jj] = 0.f;

        // fma over kk in [kbeg, kbeg+64): identical ops/order to R8's loop
        auto fma_half = [&](int kbeg) {
            #pragma unroll 8
            for (int kk2 = 0; kk2 < 64; ++kk2) {
                const int kk = kbeg + kk2;
                const float4 hv  = *(const float4*)(&hyt[(k0 + kk) * B_WG + bl0]);
                const float4 wv4 = *(const float4*)(Wp + (size_t)kk * N_HID);
                acc[0][0] = fmaf(hv.x, wv4.x, acc[0][0]);
                acc[0][1] = fmaf(hv.x, wv4.y, acc[0][1]);
                acc[0][2] = fmaf(hv.x, wv4.z, acc[0][2]);
                acc[0][3] = fmaf(hv.x, wv4.w, acc[0][3]);
                acc[1][0] = fmaf(hv.y, wv4.x, acc[1][0]);
                acc[1][1] = fmaf(hv.y, wv4.y, acc[1][1]);
                acc[1][2] = fmaf(hv.y, wv4.z, acc[1][2]);
                acc[1][3] = fmaf(hv.y, wv4.w, acc[1][3]);
                acc[2][0] = fmaf(hv.z, wv4.x, acc[2][0]);
                acc[2][1] = fmaf(hv.z, wv4.y, acc[2][1]);
                acc[2][2] = fmaf(hv.z, wv4.z, acc[2][2]);
                acc[2][3] = fmaf(hv.z, wv4.w, acc[2][3]);
                acc[3][0] = fmaf(hv.w, wv4.x, acc[3][0]);
                acc[3][1] = fmaf(hv.w, wv4.y, acc[3][1]);
                acc[3][2] = fmaf(hv.w, wv4.z, acc[3][2]);
                acc[3][3] = fmaf(hv.w, wv4.w, acc[3][3]);
            }
        };

        if (t == 0) {
            // hy(0) == 0 exactly: wave-local zero fill (no cross-wave dep)
            u64* s64 = (u64*)hyt;
            #pragma unroll
            for (int it = 0; it < 16; ++it)
                s64[(wv << 10) + it * 64 + lane] = 0ull;
            fma_half(0);
            fma_half(64);
        } else {
            const u32 ep = (u32)t;
            // half A: wave-relative chunks it in {0..7} u {16..23}
            //   (rows [0,64) and [128,192) of this wave's 256-row range,
            //    consumed by fma kk 0..63 of both k-segments)
            u64 ta[16];
            #pragma unroll
            for (int i = 0; i < 16; ++i) {
                const int it = (i < 8) ? i : (i + 8);
                const int e  = it * 64 + lane;
                const int k  = (wv << 8) + (e >> 3);
                ta[i] = a_ld64(srcU + (size_t)k * NBATCH + b0 + (e & 7));
            }
            #pragma unroll
            for (int i = 0; i < 16; ++i) {
                const int it = (i < 8) ? i : (i + 8);
                const int e  = it * 64 + lane;
                const int k  = (wv << 8) + (e >> 3);
                u64 v = ta[i];
                while ((u32)(v >> 32) != ep) {
                    __builtin_amdgcn_s_sleep(1);
                    v = a_ld64(srcU + (size_t)k * NBATCH + b0 + (e & 7));
                }
                hyt[k * B_WG + (e & 7)] = __uint_as_float((u32)v);
            }
            // issue half B loads now; latency hides under fma_half(0)
            u64 tb[16];
            #pragma unroll
            for (int i = 0; i < 16; ++i) {
                const int it = (i < 8) ? (i + 8) : (i + 16);  // {8..15,24..31}
                const int e  = it * 64 + lane;
                const int k  = (wv << 8) + (e >> 3);
                tb[i] = a_ld64(srcU + (size_t)k * NBATCH + b0 + (e & 7));
            }
            fma_half(0);
            #pragma unroll
            for (int i = 0; i < 16; ++i) {
                const int it = (i < 8) ? (i + 8) : (i + 16);
                const int e  = it * 64 + lane;
                const int k  = (wv << 8) + (e >> 3);
                u64 v = tb[i];
                while ((u32)(v >> 32) != ep) {
                    __builtin_amdgcn_s_sleep(1);
                    v = a_ld64(srcU + (size_t)k * NBATCH + b0 + (e & 7));
                }
                hyt[k * B_WG + (e & 7)] = __uint_as_float((u32)v);
            }
            fma_half(64);
        }

        // ---- k-segment partials -> LDS ----
        #pragma unroll
        for (int bi = 0; bi < 4; ++bi) {
            float4 v = make_float4(acc[bi][0], acc[bi][1], acc[bi][2], acc[bi][3]);
            *(float4*)(&part[((ks * B_WG) + bl0 + bi) * C_WG + cg * 4]) = v;
        }
        __syncthreads();   // the ONE barrier: partials + staged rows visible

        // ---- reduce k-segments (ascending, R5 order) + fused cell +
        //      direct packed store (epoch = t+1) ----
        {
            float sum = part[(0 * B_WG + bl_a) * C_WG + c_e];
            #pragma unroll
            for (int s2 = 1; s2 < KSPL; ++s2)
                sum += part[(s2 * B_WG + bl_a) * C_WG + c_e];
            const float pre = tanhf(fmaf(xa, x2h_c, sum) + bias_c);
            const float hyv = hyt[cgl * B_WG + bl_a];
            hz_a = fmaf(DT, pre - gam_c * hyv - eps_c * hz_a, hz_a);
            const float hyn = fmaf(DT, hz_a, hyv);
            const int s = ((hyn - THETA) > 0.f) ? 1 : 0;
            u_a = fmaf(u_a, alpha, (float)s * oma);
            spikes += (u32)s;
            const u64 pv = ((u64)(u32)(t + 1) << 32) | (u64)__float_as_uint(hyn);
            a_st64(dstU + (size_t)cgl * NBATCH + b0 + bl_a, pv);
        }
        {
            float sum = part[(0 * B_WG + bl_b) * C_WG + c_e];
            #pragma unroll
            for (int s2 = 1; s2 < KSPL; ++s2)
                sum += part[(s2 * B_WG + bl_b) * C_WG + c_e];
            const float pre = tanhf(fmaf(xb, x2h_c, sum) + bias_c);
            const float hyv = hyt[cgl * B_WG + bl_b];
            hz_b = fmaf(DT, pre - gam_c * hyv - eps_c * hz_b, hz_b);
            const float hyn = fmaf(DT, hz_b, hyv);
            const int s = ((hyn - THETA) > 0.f) ? 1 : 0;
            u_b = fmaf(u_b, alpha, (float)s * oma);
            spikes += (u32)s;
            const u64 pv = ((u64)(u32)(t + 1) << 32) | (u64)__float_as_uint(hyn);
            a_st64(dstU + (size_t)cgl * NBATCH + b0 + bl_b, pv);
        }
        // no end-of-step barrier: next step uses the other LDS parity, and
        // cross-WG consumption is gated element-wise by the epoch spins
    }

    // ---- final: u out, spike-count reduce ----
    uout[(size_t)(b0 + bl_a) * N_HID + cgl] = u_a;
    uout[(size_t)(b0 + bl_b) * N_HID + cgl] = u_b;

    u32 s = spikes;
    s += __shfl_down(s, 32);
    s += __shfl_down(s, 16);
    s += __shfl_down(s, 8);
    s += __shfl_down(s, 4);
    s += __shfl_down(s, 2);
    s += __shfl_down(s, 1);
    if ((tid & 63) == 0) atomicAdd(&sh_cnt, s);
    __syncthreads();
    if (tid == 0) atomicAdd(ctrl + CTRL_TOT, sh_cnt);
}

__global__ void init_kernel(u32* ctrl)
{
    const int i = blockIdx.x * blockDim.x + threadIdx.x;
    if (i < CTRL_WORDS) {
        __hip_atomic_store(ctrl + i, 0u, __ATOMIC_RELAXED,
                           __HIP_MEMORY_SCOPE_AGENT);
    }
}

__global__ void final_kernel(const u32* __restrict__ ctrl,
                             float* __restrict__ out_rate)
{
    if (threadIdx.x == 0 && blockIdx.x == 0) {
        const double denom = (double)NBATCH * (double)TSTEPS * (double)N_HID;
        *out_rate = (float)((double)ctrl[CTRL_TOT] / denom);
    }
}

extern "C" void kernel_launch(void* const* d_in, const int* in_sizes, int n_in,
                              void* d_out, int out_size, void* d_ws, size_t ws_size,
                              hipStream_t stream)
{
    const float* x    = (const float*)d_in[0];
    const float* h2h  = (const float*)d_in[1];
    const float* x2h  = (const float*)d_in[2];
    const float* bias = (const float*)d_in[3];
    const float* gam  = (const float*)d_in[4];
    const float* eps  = (const float*)d_in[5];

    float* out = (float*)d_out;            // u: [0,131072), rate at [131072]

    u64* hyA  = (u64*)d_ws;                               // 1 MB
    u64* hyB  = hyA + (size_t)N_HID * NBATCH;             // 1 MB
    u32* ctrl = (u32*)(hyB + (size_t)N_HID * NBATCH);

    init_kernel<<<dim3(1), dim3(256), 0, stream>>>(ctrl);

    float alpha = expf(-1.0f / 20.0f);
    float oma   = 1.0f - alpha;

    void* args[] = {
        (void*)&x, (void*)&h2h, (void*)&x2h, (void*)&bias, (void*)&gam,
        (void*)&eps, (void*)&hyA, (void*)&hyB, (void*)&out, (void*)&ctrl,
        (void*)&alpha, (void*)&oma
    };
    hipLaunchCooperativeKernel((const void*)persist_kernel,
                               dim3(NWG), dim3(256), args, 0, stream);

    final_kernel<<<dim3(1), dim3(64), 0, stream>>>(
        ctrl, out + (size_t)NBATCH * N_HID);
}

// Round 14
// 4807.785 us; speedup vs baseline: 1.9897x; 1.9897x over previous
//
#include <hip/hip_runtime.h>
#include <math.h>

typedef unsigned long long u64;
typedef unsigned int u32;

#define N_HID   1024
#define NBATCH  128
#define TSTEPS  500
#define DT      0.05f
#define THETA   0.1f

// Geometry identical to bit-exact R8: WG = 256 thr, 8-batch x 64-col tile,
// thread tile 4b x 4c, k-split 8 (KSEG=128). 16 groups x 16 ctiles = 256 WGs,
// 1/CU cooperative. Per-output FP summation order unchanged.
// R14 = R8 minus SYNC2/sh_out, plus per-wave flag publish + parity-dbuf LDS.
// NO wreg (condemned by R10-R13), NO staging/fma interleave.
#define B_WG   8
#define C_WG   64
#define KSPL   8
#define KSEG   (N_HID / KSPL)      // 128
#define NGRP   (NBATCH / B_WG)     // 16
#define NCT    (N_HID / C_WG)      // 16
#define NWG    (NGRP * NCT)        // 256

// Sync: per-group, per-producer, PER-WAVE epoch flags. Producer (g,ct) wave w
// publishes flags_g[ct*4+w] = t+1 after draining ITS OWN hy(t+1) stores
// (s_waitcnt vmcnt(0), wave-local). Consumer wave wv polls its 4 producers'
// 16 wave-flags. All cross-WG traffic = AGENT-scope relaxed atomics (IF$).
#define CTRL_TOT    0
#define CTRL_GRP    64                      // group g: 64 flags at +g*64
#define CTRL_WORDS  (CTRL_GRP + NGRP * 64)

__device__ __forceinline__ u32 a_ld32(const u32* p) {
    return __hip_atomic_load(p, __ATOMIC_RELAXED, __HIP_MEMORY_SCOPE_AGENT);
}
__device__ __forceinline__ void a_st32(u32* p, u32 v) {
    __hip_atomic_store(p, v, __ATOMIC_RELAXED, __HIP_MEMORY_SCOPE_AGENT);
}
__device__ __forceinline__ u64 a_ld64(const u64* p) {
    return __hip_atomic_load(p, __ATOMIC_RELAXED, __HIP_MEMORY_SCOPE_AGENT);
}

// exact fma sequence (order-identical to R2..R13 kernels)
#define FMA16(hv, wv4) do { \
    acc[0][0]=fmaf((hv).x,(wv4).x,acc[0][0]); acc[0][1]=fmaf((hv).x,(wv4).y,acc[0][1]); \
    acc[0][2]=fmaf((hv).x,(wv4).z,acc[0][2]); acc[0][3]=fmaf((hv).x,(wv4).w,acc[0][3]); \
    acc[1][0]=fmaf((hv).y,(wv4).x,acc[1][0]); acc[1][1]=fmaf((hv).y,(wv4).y,acc[1][1]); \
    acc[1][2]=fmaf((hv).y,(wv4).z,acc[1][2]); acc[1][3]=fmaf((hv).y,(wv4).w,acc[1][3]); \
    acc[2][0]=fmaf((hv).z,(wv4).x,acc[2][0]); acc[2][1]=fmaf((hv).z,(wv4).y,acc[2][1]); \
    acc[2][2]=fmaf((hv).z,(wv4).z,acc[2][2]); acc[2][3]=fmaf((hv).z,(wv4).w,acc[2][3]); \
    acc[3][0]=fmaf((hv).w,(wv4).x,acc[3][0]); acc[3][1]=fmaf((hv).w,(wv4).y,acc[3][1]); \
    acc[3][2]=fmaf((hv).w,(wv4).z,acc[3][2]); acc[3][3]=fmaf((hv).w,(wv4).w,acc[3][3]); \
} while (0)

__global__ __launch_bounds__(256, 1) void persist_kernel(
    const float* __restrict__ x,
    const float* __restrict__ W,       // (1024,1024) row-major [k][c]
    const float* __restrict__ x2h,
    const float* __restrict__ bias,
    const float* __restrict__ gam,
    const float* __restrict__ eps,
    float* __restrict__ hyT0,          // (1024,128) ping
    float* __restrict__ hyT1,          // (1024,128) pong
    float* __restrict__ uout,          // (128,1024)
    u32* __restrict__ ctrl,
    float alpha, float oma)
{
    // parity double-buffered LDS: wave skew is bounded to 1 step by SYNC1,
    // and adjacent steps touch opposite buffers -> single barrier per step.
    __shared__ float sh_hyT[2][N_HID * B_WG];         // 2 x 32 KB [k][8b]
    __shared__ float sh_part[2][KSPL * B_WG * C_WG];  // 2 x 16 KB [ks][b][c]
    __shared__ u32 sh_cnt;

    const int tid = threadIdx.x;
    if (tid == 0) sh_cnt = 0u;

    // XCD swizzle (R5): XCD (bid&7) owns 2 ctiles -> 512 KB W slice hot in L2.
    const int bid   = blockIdx.x;
    const int xcd   = bid & 7;
    const int idx   = bid >> 3;
    const int ctile = xcd * 2 + (idx & 1);
    const int btile = idx >> 1;
    const int c0g   = ctile * C_WG;
    const int b0    = btile * B_WG;

    // GEMM thread mapping (R8)
    const int cg  = tid & 15;
    const int bg  = (tid >> 4) & 1;
    const int ks  = tid >> 5;          // 0..7
    const int bl0 = bg * 4;
    const int k0  = ks * KSEG;
    const float* Wp = W + (size_t)k0 * N_HID + c0g + cg * 4;

    // wave staging mapping (R8): wave wv owns hy rows [256*wv, 256*wv+256)
    const int wv   = tid >> 6;         // 0..3
    const int lane = tid & 63;
    u32* flags = ctrl + CTRL_GRP + (btile << 6);     // 64 flags (256 B)
    // consumer wave wv needs producers p = 4wv..4wv+3, all 4 waves each:
    // flag indices p*4+w = 16*wv + (0..15)
    u32* mypoll  = flags + 16 * wv + (lane & 15);
    // producer publish slot for THIS wave
    u32* mypub   = flags + ctile * 4 + wv;

    // epilogue mapping (R8): two outputs per thread
    const int bl_a = tid >> 6;
    const int bl_b = 4 + bl_a;
    const int c_e  = tid & 63;
    const int cgl  = c0g + c_e;
    const float x2h_c  = x2h[cgl];
    const float bias_c = bias[cgl];
    const float gam_c  = gam[cgl];
    const float eps_c  = eps[cgl];
    const float* xrow_a = x + (size_t)(b0 + bl_a) * TSTEPS;
    const float* xrow_b = x + (size_t)(b0 + bl_b) * TSTEPS;

    float hz_a = 0.f, hz_b = 0.f, u_a = 0.f, u_b = 0.f;
    u32 spikes = 0;

    for (int t = 0; t < TSTEPS; ++t) {
        const float* src = (t & 1) ? hyT1 : hyT0;   // hy(t)   (t>=1)
        float*       dst = (t & 1) ? hyT0 : hyT1;   // hy(t+1)
        float* hyt  = sh_hyT[t & 1];
        float* part = sh_part[t & 1];

        // x prefetch: issue early so latency hides under poll+stage+fma
        const float xa = xrow_a[t];
        const float xb = xrow_b[t];

        // ---- acquire hy(t) rows for this wave (R8 addressing) ----
        if (t == 0) {
            // hy(0) == 0 exactly: zero-fill (no memory read, no poll)
            u64* s64 = (u64*)hyt;
            #pragma unroll
            for (int it = 0; it < 16; ++it)
                s64[(wv << 10) + it * 64 + lane] = 0ull;
        } else {
            // poll this wave's 4 producers x 4 waves (epoch >= t)
            while (!__all(a_ld32(mypoll) >= (u32)t))
                __builtin_amdgcn_s_sleep(1);
            // stage rows [256*wv, 256*wv+256) x 8 batches (8 KB), IF$ loads
            u64 tmp[16];
            #pragma unroll
            for (int it = 0; it < 16; ++it) {
                const int i    = it * 64 + lane;        // 0..1023
                const int k    = (wv << 8) + (i >> 2);
                const int pair = i & 3;
                const u64* sp = (const u64*)(src + (size_t)k * NBATCH + b0) + pair;
                tmp[it] = a_ld64(sp);
            }
            u64* s64 = (u64*)hyt;
            #pragma unroll
            for (int it = 0; it < 16; ++it)
                s64[(wv << 10) + it * 64 + lane] = tmp[it];
            // no barrier: this wave's fma reads only rows it just wrote
            // (same-wave ds-order; identical pattern proven green in R8)
        }

        // ---- register-blocked GEMM: 4b x 4c, kseg = 128 (order-exact) ----
        float acc[4][4];
        #pragma unroll
        for (int i = 0; i < 4; ++i)
            #pragma unroll
            for (int jj = 0; jj < 4; ++jj) acc[i][jj] = 0.f;

        #pragma unroll 8
        for (int kk = 0; kk < KSEG; ++kk) {
            const float4 hv  = *(const float4*)(&hyt[(k0 + kk) * B_WG + bl0]);
            const float4 wv4 = *(const float4*)(Wp + (size_t)kk * N_HID);
            FMA16(hv, wv4);
        }

        #pragma unroll
        for (int bi = 0; bi < 4; ++bi) {
            float4 v = make_float4(acc[bi][0], acc[bi][1], acc[bi][2], acc[bi][3]);
            *(float4*)(&part[((ks * B_WG) + bl0 + bi) * C_WG + cg * 4]) = v;
        }
        __syncthreads();   // SYNC1: this step's partials + staged rows visible

        // ---- reduce k-segments (ascending, R8 order) + fused cell +
        //      DIRECT hy(t+1) stores from registers (scattered 4B, IF$) ----
        {
            float sum = part[(0 * B_WG + bl_a) * C_WG + c_e];
            #pragma unroll
            for (int s2 = 1; s2 < KSPL; ++s2)
                sum += part[(s2 * B_WG + bl_a) * C_WG + c_e];
            const float pre = tanhf(fmaf(xa, x2h_c, sum) + bias_c);
            const float hyv = hyt[cgl * B_WG + bl_a];
            hz_a = fmaf(DT, pre - gam_c * hyv - eps_c * hz_a, hz_a);
            const float hyn = fmaf(DT, hz_a, hyv);
            const int s = ((hyn - THETA) > 0.f) ? 1 : 0;
            u_a = fmaf(u_a, alpha, (float)s * oma);
            spikes += (u32)s;
            a_st32((u32*)(dst + (size_t)cgl * NBATCH + b0 + bl_a),
                   __float_as_uint(hyn));
        }
        {
            float sum = part[(0 * B_WG + bl_b) * C_WG + c_e];
            #pragma unroll
            for (int s2 = 1; s2 < KSPL; ++s2)
                sum += part[(s2 * B_WG + bl_b) * C_WG + c_e];
            const float pre = tanhf(fmaf(xb, x2h_c, sum) + bias_c);
            const float hyv = hyt[cgl * B_WG + bl_b];
            hz_b = fmaf(DT, pre - gam_c * hyv - eps_c * hz_b, hz_b);
            const float hyn = fmaf(DT, hz_b, hyv);
            const int s = ((hyn - THETA) > 0.f) ? 1 : 0;
            u_b = fmaf(u_b, alpha, (float)s * oma);
            spikes += (u32)s;
            a_st32((u32*)(dst + (size_t)cgl * NBATCH + b0 + bl_b),
                   __float_as_uint(hyn));
        }

        // ---- per-wave publish: drain OWN stores, then flag = t+1 ----
        asm volatile("s_waitcnt vmcnt(0)" ::: "memory");
        if (lane == 0) a_st32(mypub, (u32)(t + 1));
        // no end-of-step barrier: SYNC1 bounds skew to 1 step and the
        // parity buffers make adjacent-step LDS use disjoint.
    }

    // ---- final: u out, spike-count reduce ----
    uout[(size_t)(b0 + bl_a) * N_HID + cgl] = u_a;
    uout[(size_t)(b0 + bl_b) * N_HID + cgl] = u_b;

    u32 s = spikes;
    s += __shfl_down(s, 32);
    s += __shfl_down(s, 16);
    s += __shfl_down(s, 8);
    s += __shfl_down(s, 4);
    s += __shfl_down(s, 2);
    s += __shfl_down(s, 1);
    if ((tid & 63) == 0) atomicAdd(&sh_cnt, s);
    __syncthreads();
    if (tid == 0) atomicAdd(ctrl + CTRL_TOT, sh_cnt);
}

__global__ void init_kernel(u32* ctrl)
{
    const int i = blockIdx.x * blockDim.x + threadIdx.x;
    if (i < CTRL_WORDS) {
        __hip_atomic_store(ctrl + i, 0u, __ATOMIC_RELAXED,
                           __HIP_MEMORY_SCOPE_AGENT);
    }
}

__global__ void final_kernel(const u32* __restrict__ ctrl,
                             float* __restrict__ out_rate)
{
    if (threadIdx.x == 0 && blockIdx.x == 0) {
        const double denom = (double)NBATCH * (double)TSTEPS * (double)N_HID;
        *out_rate = (float)((double)ctrl[CTRL_TOT] / denom);
    }
}

extern "C" void kernel_launch(void* const* d_in, const int* in_sizes, int n_in,
                              void* d_out, int out_size, void* d_ws, size_t ws_size,
                              hipStream_t stream)
{
    const float* x    = (const float*)d_in[0];
    const float* h2h  = (const float*)d_in[1];
    const float* x2h  = (const float*)d_in[2];
    const float* bias = (const float*)d_in[3];
    const float* gam  = (const float*)d_in[4];
    const float* eps  = (const float*)d_in[5];

    float* out = (float*)d_out;            // u: [0,131072), rate at [131072]

    float* hyT0 = (float*)d_ws;
    float* hyT1 = hyT0 + (size_t)NBATCH * N_HID;
    u32*   ctrl = (u32*)(hyT1 + (size_t)NBATCH * N_HID);

    init_kernel<<<dim3((CTRL_WORDS + 255) / 256), dim3(256), 0, stream>>>(ctrl);

    float alpha = expf(-1.0f / 20.0f);
    float oma   = 1.0f - alpha;

    void* args[] = {
        (void*)&x, (void*)&h2h, (void*)&x2h, (void*)&bias, (void*)&gam,
        (void*)&eps, (void*)&hyT0, (void*)&hyT1, (void*)&out, (void*)&ctrl,
        (void*)&alpha, (void*)&oma
    };
    hipLaunchCooperativeKernel((const void*)persist_kernel,
                               dim3(NWG), dim3(256), args, 0, stream);

    final_kernel<<<dim3(1), dim3(64), 0, stream>>>(
        ctrl, out + (size_t)NBATCH * N_HID);
}

// Round 15
// 4107.644 us; speedup vs baseline: 2.3289x; 1.1704x over previous
//
#include <hip/hip_runtime.h>
#include <math.h>

typedef unsigned long long u64;
typedef unsigned int u32;

#define N_HID   1024
#define NBATCH  128
#define TSTEPS  500
#define DT      0.05f
#define THETA   0.1f

// Geometry identical to bit-exact R8: WG = 256 thr, 8-batch x 64-col tile,
// thread tile 4b x 4c, k-split 8 (KSEG=128). 16 groups x 16 ctiles = 256 WGs,
// 1/CU cooperative. Per-output FP summation order unchanged.
// R15 = R14 with the epilogue remapped so each thread computes the two
// outputs it stores CONTIGUOUSLY (row c2, batches b2..b2+1) -> one packed
// u64 store, coalesced like R8, but with no sh_out buffer and no extra
// barrier. Per-wave flag publish after own-store vmcnt drain (R14).
#define B_WG   8
#define C_WG   64
#define KSPL   8
#define KSEG   (N_HID / KSPL)      // 128
#define NGRP   (NBATCH / B_WG)     // 16
#define NCT    (N_HID / C_WG)      // 16
#define NWG    (NGRP * NCT)        // 256

// Sync: per-group, per-producer, PER-WAVE epoch flags (R14-proven).
#define CTRL_TOT    0
#define CTRL_GRP    64                      // group g: 64 flags at +g*64
#define CTRL_WORDS  (CTRL_GRP + NGRP * 64)

__device__ __forceinline__ u32 a_ld32(const u32* p) {
    return __hip_atomic_load(p, __ATOMIC_RELAXED, __HIP_MEMORY_SCOPE_AGENT);
}
__device__ __forceinline__ void a_st32(u32* p, u32 v) {
    __hip_atomic_store(p, v, __ATOMIC_RELAXED, __HIP_MEMORY_SCOPE_AGENT);
}
__device__ __forceinline__ u64 a_ld64(const u64* p) {
    return __hip_atomic_load(p, __ATOMIC_RELAXED, __HIP_MEMORY_SCOPE_AGENT);
}
__device__ __forceinline__ void a_st64(u64* p, u64 v) {
    __hip_atomic_store(p, v, __ATOMIC_RELAXED, __HIP_MEMORY_SCOPE_AGENT);
}

// exact fma sequence (order-identical to R2..R14 kernels)
#define FMA16(hv, wv4) do { \
    acc[0][0]=fmaf((hv).x,(wv4).x,acc[0][0]); acc[0][1]=fmaf((hv).x,(wv4).y,acc[0][1]); \
    acc[0][2]=fmaf((hv).x,(wv4).z,acc[0][2]); acc[0][3]=fmaf((hv).x,(wv4).w,acc[0][3]); \
    acc[1][0]=fmaf((hv).y,(wv4).x,acc[1][0]); acc[1][1]=fmaf((hv).y,(wv4).y,acc[1][1]); \
    acc[1][2]=fmaf((hv).y,(wv4).z,acc[1][2]); acc[1][3]=fmaf((hv).y,(wv4).w,acc[1][3]); \
    acc[2][0]=fmaf((hv).z,(wv4).x,acc[2][0]); acc[2][1]=fmaf((hv).z,(wv4).y,acc[2][1]); \
    acc[2][2]=fmaf((hv).z,(wv4).z,acc[2][2]); acc[2][3]=fmaf((hv).z,(wv4).w,acc[2][3]); \
    acc[3][0]=fmaf((hv).w,(wv4).x,acc[3][0]); acc[3][1]=fmaf((hv).w,(wv4).y,acc[3][1]); \
    acc[3][2]=fmaf((hv).w,(wv4).z,acc[3][2]); acc[3][3]=fmaf((hv).w,(wv4).w,acc[3][3]); \
} while (0)

__global__ __launch_bounds__(256, 1) void persist_kernel(
    const float* __restrict__ x,
    const float* __restrict__ W,       // (1024,1024) row-major [k][c]
    const float* __restrict__ x2h,
    const float* __restrict__ bias,
    const float* __restrict__ gam,
    const float* __restrict__ eps,
    float* __restrict__ hyT0,          // (1024,128) ping
    float* __restrict__ hyT1,          // (1024,128) pong
    float* __restrict__ uout,          // (128,1024)
    u32* __restrict__ ctrl,
    float alpha, float oma)
{
    // parity double-buffered LDS: single barrier per step (SYNC1)
    __shared__ float sh_hyT[2][N_HID * B_WG];         // 2 x 32 KB [k][8b]
    __shared__ float sh_part[2][KSPL * B_WG * C_WG];  // 2 x 16 KB [ks][b][c]
    __shared__ u32 sh_cnt;

    const int tid = threadIdx.x;
    if (tid == 0) sh_cnt = 0u;

    // XCD swizzle (R5): XCD (bid&7) owns 2 ctiles -> 512 KB W slice hot in L2.
    const int bid   = blockIdx.x;
    const int xcd   = bid & 7;
    const int idx   = bid >> 3;
    const int ctile = xcd * 2 + (idx & 1);
    const int btile = idx >> 1;
    const int c0g   = ctile * C_WG;
    const int b0    = btile * B_WG;

    // GEMM thread mapping (R8)
    const int cg  = tid & 15;
    const int bg  = (tid >> 4) & 1;
    const int ks  = tid >> 5;          // 0..7
    const int bl0 = bg * 4;
    const int k0  = ks * KSEG;
    const float* Wp = W + (size_t)k0 * N_HID + c0g + cg * 4;

    // wave staging mapping (R8): wave wv owns hy rows [256*wv, 256*wv+256)
    const int wv   = tid >> 6;         // 0..3
    const int lane = tid & 63;
    u32* flags = ctrl + CTRL_GRP + (btile << 6);     // 64 flags (256 B)
    u32* mypoll = flags + 16 * wv + (lane & 15);     // 4 producers x 4 waves
    u32* mypub  = flags + ctile * 4 + wv;            // this wave's slot

    // epilogue mapping (NEW): thread owns (row c2, batches b2, b2+1)
    const int c2  = tid >> 2;          // 0..63  (wave wv: c2 in [16wv,16wv+16))
    const int b2  = (tid & 3) * 2;     // 0,2,4,6
    const int cgl = c0g + c2;
    const float x2h_c  = x2h[cgl];
    const float bias_c = bias[cgl];
    const float gam_c  = gam[cgl];
    const float eps_c  = eps[cgl];
    const float* xrow0 = x + (size_t)(b0 + b2)     * TSTEPS;
    const float* xrow1 = x + (size_t)(b0 + b2 + 1) * TSTEPS;

    float hz0 = 0.f, hz1 = 0.f, u0 = 0.f, u1 = 0.f;
    u32 spikes = 0;

    for (int t = 0; t < TSTEPS; ++t) {
        const float* src = (t & 1) ? hyT1 : hyT0;   // hy(t)   (t>=1)
        float*       dst = (t & 1) ? hyT0 : hyT1;   // hy(t+1)
        float* hyt  = sh_hyT[t & 1];
        float* part = sh_part[t & 1];

        // x prefetch: latency hides under poll+stage+fma
        const float xa = xrow0[t];
        const float xb = xrow1[t];

        // ---- acquire hy(t) rows for this wave (R8 addressing) ----
        if (t == 0) {
            u64* s64 = (u64*)hyt;
            #pragma unroll
            for (int it = 0; it < 16; ++it)
                s64[(wv << 10) + it * 64 + lane] = 0ull;
        } else {
            while (!__all(a_ld32(mypoll) >= (u32)t))
                __builtin_amdgcn_s_sleep(1);
            u64 tmp[16];
            #pragma unroll
            for (int it = 0; it < 16; ++it) {
                const int i    = it * 64 + lane;        // 0..1023
                const int k    = (wv << 8) + (i >> 2);
                const int pair = i & 3;
                const u64* sp = (const u64*)(src + (size_t)k * NBATCH + b0) + pair;
                tmp[it] = a_ld64(sp);
            }
            u64* s64 = (u64*)hyt;
            #pragma unroll
            for (int it = 0; it < 16; ++it)
                s64[(wv << 10) + it * 64 + lane] = tmp[it];
            // no barrier: this wave's fma reads only rows it just wrote
            // (same-wave ds-order; pattern proven green in R8/R14)
        }

        // ---- register-blocked GEMM: 4b x 4c, kseg = 128 (order-exact) ----
        float acc[4][4];
        #pragma unroll
        for (int i = 0; i < 4; ++i)
            #pragma unroll
            for (int jj = 0; jj < 4; ++jj) acc[i][jj] = 0.f;

        #pragma unroll 8
        for (int kk = 0; kk < KSEG; ++kk) {
            const float4 hv  = *(const float4*)(&hyt[(k0 + kk) * B_WG + bl0]);
            const float4 wv4 = *(const float4*)(Wp + (size_t)kk * N_HID);
            FMA16(hv, wv4);
        }

        #pragma unroll
        for (int bi = 0; bi < 4; ++bi) {
            float4 v = make_float4(acc[bi][0], acc[bi][1], acc[bi][2], acc[bi][3]);
            *(float4*)(&part[((ks * B_WG) + bl0 + bi) * C_WG + cg * 4]) = v;
        }
        __syncthreads();   // SYNC1: partials + staged rows visible

        // ---- reduce (ascending, R8 order) + fused cell, both batches of
        //      this thread's row; then ONE packed coalesced u64 store ----
        float hyn0, hyn1;
        {
            float sum = part[(0 * B_WG + b2) * C_WG + c2];
            #pragma unroll
            for (int s2 = 1; s2 < KSPL; ++s2)
                sum += part[(s2 * B_WG + b2) * C_WG + c2];
            const float pre = tanhf(fmaf(xa, x2h_c, sum) + bias_c);
            const float hyv = hyt[cgl * B_WG + b2];
            hz0 = fmaf(DT, pre - gam_c * hyv - eps_c * hz0, hz0);
            hyn0 = fmaf(DT, hz0, hyv);
            const int s = ((hyn0 - THETA) > 0.f) ? 1 : 0;
            u0 = fmaf(u0, alpha, (float)s * oma);
            spikes += (u32)s;
        }
        {
            float sum = part[(0 * B_WG + b2 + 1) * C_WG + c2];
            #pragma unroll
            for (int s2 = 1; s2 < KSPL; ++s2)
                sum += part[(s2 * B_WG + b2 + 1) * C_WG + c2];
            const float pre = tanhf(fmaf(xb, x2h_c, sum) + bias_c);
            const float hyv = hyt[cgl * B_WG + b2 + 1];
            hz1 = fmaf(DT, pre - gam_c * hyv - eps_c * hz1, hz1);
            hyn1 = fmaf(DT, hz1, hyv);
            const int s = ((hyn1 - THETA) > 0.f) ? 1 : 0;
            u1 = fmaf(u1, alpha, (float)s * oma);
            spikes += (u32)s;
        }
        {
            float2 f2 = make_float2(hyn0, hyn1);
            u64 v;
            __builtin_memcpy(&v, &f2, 8);
            a_st64((u64*)(dst + (size_t)cgl * NBATCH + b0 + b2), v);
        }

        // ---- per-wave publish: drain OWN stores, then flag = t+1 ----
        asm volatile("s_waitcnt vmcnt(0)" ::: "memory");
        if (lane == 0) a_st32(mypub, (u32)(t + 1));
        // no end-of-step barrier: SYNC1 bounds skew; parity buffers disjoint
    }

    // ---- final: u out, spike-count reduce ----
    uout[(size_t)(b0 + b2)     * N_HID + cgl] = u0;
    uout[(size_t)(b0 + b2 + 1) * N_HID + cgl] = u1;

    u32 s = spikes;
    s += __shfl_down(s, 32);
    s += __shfl_down(s, 16);
    s += __shfl_down(s, 8);
    s += __shfl_down(s, 4);
    s += __shfl_down(s, 2);
    s += __shfl_down(s, 1);
    if ((tid & 63) == 0) atomicAdd(&sh_cnt, s);
    __syncthreads();
    if (tid == 0) atomicAdd(ctrl + CTRL_TOT, sh_cnt);
}

__global__ void init_kernel(u32* ctrl)
{
    const int i = blockIdx.x * blockDim.x + threadIdx.x;
    if (i < CTRL_WORDS) {
        __hip_atomic_store(ctrl + i, 0u, __ATOMIC_RELAXED,
                           __HIP_MEMORY_SCOPE_AGENT);
    }
}

__global__ void final_kernel(const u32* __restrict__ ctrl,
                             float* __restrict__ out_rate)
{
    if (threadIdx.x == 0 && blockIdx.x == 0) {
        const double denom = (double)NBATCH * (double)TSTEPS * (double)N_HID;
        *out_rate = (float)((double)ctrl[CTRL_TOT] / denom);
    }
}

extern "C" void kernel_launch(void* const* d_in, const int* in_sizes, int n_in,
                              void* d_out, int out_size, void* d_ws, size_t ws_size,
                              hipStream_t stream)
{
    const float* x    = (const float*)d_in[0];
    const float* h2h  = (const float*)d_in[1];
    const float* x2h  = (const float*)d_in[2];
    const float* bias = (const float*)d_in[3];
    const float* gam  = (const float*)d_in[4];
    const float* eps  = (const float*)d_in[5];

    float* out = (float*)d_out;            // u: [0,131072), rate at [131072]

    float* hyT0 = (float*)d_ws;
    float* hyT1 = hyT0 + (size_t)NBATCH * N_HID;
    u32*   ctrl = (u32*)(hyT1 + (size_t)NBATCH * N_HID);

    init_kernel<<<dim3((CTRL_WORDS + 255) / 256), dim3(256), 0, stream>>>(ctrl);

    float alpha = expf(-1.0f / 20.0f);
    float oma   = 1.0f - alpha;

    void* args[] = {
        (void*)&x, (void*)&h2h, (void*)&x2h, (void*)&bias, (void*)&gam,
        (void*)&eps, (void*)&hyT0, (void*)&hyT1, (void*)&out, (void*)&ctrl,
        (void*)&alpha, (void*)&oma
    };
    hipLaunchCooperativeKernel((const void*)persist_kernel,
                               dim3(NWG), dim3(256), args, 0, stream);

    final_kernel<<<dim3(1), dim3(64), 0, stream>>>(
        ctrl, out + (size_t)NBATCH * N_HID);
}